// Round 4
// baseline (364.799 us; speedup 1.0000x reference)
//
#include <hip/hip_runtime.h>
#include <math.h>

#define NPTS   500000
#define NB     256
#define TOPK   10
#define CAP    2048        // per-query candidate cap in k_final
#define SBLK   1024        // sample slices
#define SPER   16          // points per slice -> 16384-pt sample, tighter tau
#define MARGIN 2.0f        // bf16 worst-case score err ~0.5; 4x headroom
#define FBLK   768         // k_filter grid (3 chunk-streams/CU at 4 blk/CU target)
#define NCHUNK 3907        // ceil(NPTS/128)
#define LCAP   11          // per-(block,query) local cap (lambda <= ~1.5)
#define QS2    36          // shorts per row in LDS (72 B: 8-B aligned, 18-bank stride)
#define PCAP   524288      // pair buffer capacity (2 MB)

typedef short v4s  __attribute__((ext_vector_type(4)));
typedef short v8s  __attribute__((ext_vector_type(8)));
typedef float v16f __attribute__((ext_vector_type(16)));

__device__ __forceinline__ unsigned short f2bf(float f) {   // RNE
    unsigned u = __float_as_uint(f);
    unsigned r = u + 0x7FFFu + ((u >> 16) & 1u);
    return (unsigned short)(r >> 16);
}
__device__ __forceinline__ float bf2f(unsigned short h) {
    return __uint_as_float(((unsigned)h) << 16);
}
__device__ __forceinline__ float bf2fs(short h) {
    return __uint_as_float(((unsigned)(unsigned short)h) << 16);
}

// --- exact fp32 pieces: bitwise-identical order in k_sample and k_final -----
__device__ __forceinline__ float norm34(const float* __restrict__ r) {
    float a0 = 0.f, a1 = 0.f, a2 = 0.f, a3 = 0.f;
#pragma unroll
    for (int d = 0; d < 32; d += 4) {
        a0 = fmaf(r[d + 0], r[d + 0], a0);
        a1 = fmaf(r[d + 1], r[d + 1], a1);
        a2 = fmaf(r[d + 2], r[d + 2], a2);
        a3 = fmaf(r[d + 3], r[d + 3], a3);
    }
    a0 = fmaf(r[32], r[32], a0);
    a1 = fmaf(r[33], r[33], a1);
    return (a0 + a1) + (a2 + a3);
}
__device__ __forceinline__ float dot34(const float* __restrict__ r, const float* q) {
    float a0 = 0.f, a1 = 0.f, a2 = 0.f, a3 = 0.f;
#pragma unroll
    for (int d = 0; d < 32; d += 4) {
        a0 = fmaf(r[d + 0], q[d + 0], a0);
        a1 = fmaf(r[d + 1], q[d + 1], a1);
        a2 = fmaf(r[d + 2], q[d + 2], a2);
        a3 = fmaf(r[d + 3], q[d + 3], a3);
    }
    a0 = fmaf(r[32], q[32], a0);
    a1 = fmaf(r[33], q[33], a1);
    return (a0 + a1) + (a2 + a3);
}
// float4 LDS variant with IDENTICAL fma order -> bitwise-equal s
__device__ __forceinline__ float dot34_v4(const float4* __restrict__ r4, const float* q) {
    float a0 = 0.f, a1 = 0.f, a2 = 0.f, a3 = 0.f;
#pragma unroll
    for (int dp = 0; dp < 8; ++dp) {
        float4 v = r4[dp];
        a0 = fmaf(v.x, q[4 * dp + 0], a0);
        a1 = fmaf(v.y, q[4 * dp + 1], a1);
        a2 = fmaf(v.z, q[4 * dp + 2], a2);
        a3 = fmaf(v.w, q[4 * dp + 3], a3);
    }
    float2 t = *(const float2*)(r4 + 8);
    a0 = fmaf(t.x, q[32], a0);
    a1 = fmaf(t.y, q[33], a1);
    return (a0 + a1) + (a2 + a3);
}
__device__ __forceinline__ void load_q(const float* __restrict__ obs,
                                       const float* __restrict__ act, int b, float* q) {
#pragma unroll
    for (int d = 0; d < 32; ++d) q[d] = obs[b * 32 + d];
    q[32] = act[b * 2 + 0];
    q[33] = act[b * 2 + 1];
}

// --- kernel 0a: per-(query, 16-pt slice) min of s; minima transposed --------
__global__ __launch_bounds__(256, 4) void k_sample(const float* __restrict__ obs,
                                                   const float* __restrict__ act,
                                                   const float* __restrict__ msa,
                                                   float* __restrict__ minima) {
    __shared__ __align__(16) float sm[SPER * 36];
    __shared__ float smn[SPER];
    const int g = blockIdx.x, t = threadIdx.x;
    const int base = g * SPER;
    for (int i = t; i < SPER * 34; i += 256) {
        int row = i / 34, d = i - row * 34;
        sm[row * 36 + d] = msa[(size_t)base * 34 + i];
    }
    __syncthreads();
    if (t < SPER) smn[t] = norm34(&sm[t * 36]);
    __syncthreads();
    float q[34];
    load_q(obs, act, t, q);
    float best = __builtin_inff();
#pragma unroll
    for (int j = 0; j < SPER; ++j) {
        float s = fmaf(-2.f, dot34_v4((const float4*)&sm[j * 36], q), smn[j]);
        best = fminf(best, s);
    }
    minima[(size_t)t * SBLK + g] = best;          // transposed: k_tau coalesced
}

// --- kernel 0b: tau = 10th smallest of 1024 slice-minima; emit q-hat; cursor0
__global__ __launch_bounds__(64) void k_tau(const float* __restrict__ minima,
                                            const float* __restrict__ obs,
                                            const float* __restrict__ act,
                                            unsigned short* __restrict__ qbf,
                                            int* __restrict__ cursor) {
    const int b = blockIdx.x, lane = threadIdx.x;
    if (b == 0 && lane == 0) *cursor = 0;
    float v[16];
#pragma unroll
    for (int k = 0; k < 16; ++k) v[k] = minima[(size_t)b * SBLK + lane + 64 * k];
    float last = 0.f;
    for (int r = 0; r < TOPK; ++r) {
        float lm = v[0]; int la = 0;
#pragma unroll
        for (int k = 1; k < 16; ++k) { if (v[k] < lm) { lm = v[k]; la = k; } }
        float wm = lm;
        for (int off = 32; off; off >>= 1) wm = fminf(wm, __shfl_xor(wm, off));
        unsigned long long msk = __ballot(lm == wm);
        int first = (int)__builtin_ctzll(msk);
        if (lane == first) {
#pragma unroll
            for (int k = 0; k < 16; ++k) { if (k == la) v[k] = __builtin_inff(); }
        }
        last = wm;   // wave-uniform
    }
    // q-hat row (36 shorts): [q(34), -0.5, (tau+MARGIN)/2]
    float val = 0.f;
    if (lane < 32)       val = obs[b * 32 + lane];
    else if (lane < 34)  val = act[b * 2 + (lane - 32)];
    else if (lane == 34) val = -0.5f;
    else if (lane == 35) val = 0.5f * (last + MARGIN);
    if (lane < QS2) qbf[b * QS2 + lane] = f2bf(val);
}

// --- kernel 1: MFMA bf16 filter -> flat pair list (q<<19|p), 1 atomic/block -
__global__ __launch_bounds__(256, 4) void k_filter(const float* __restrict__ msa,
                                                   const unsigned short* __restrict__ qbf,
                                                   int* __restrict__ cursor,
                                                   unsigned* __restrict__ pbuf) {
    __shared__ __align__(16) unsigned short lq[NB * QS2];    // 18432 B
    __shared__ __align__(16) unsigned short lm[128 * QS2];   // 9216 B
    __shared__ int lcount[NB];                               // 1024 B
    __shared__ int lcand[NB * LCAP];                         // 11264 B
    __shared__ int gbase;
    const int g = blockIdx.x, t = threadIdx.x;
    lcount[t] = 0;
    // stage all 256 q-hat rows once (pre-converted bf16)
    const float4* qsrc = (const float4*)qbf;
    for (int i = t; i < NB * QS2 / 8; i += 256)
        *(float4*)&lq[i * 8] = qsrc[i];
    const int w = t >> 6, lane = t & 63;
    const int mrow = lane & 31, half = lane >> 5;
    const v8s vz8 = (v8s)(short)0;
    const v4s vz4 = (v4s)(short)0;
    for (int c = g; c < NCHUNK; c += FBLK) {
        const int lo = c * 128;
        __syncthreads();                       // lm safe to overwrite (also covers lq/lcount on iter 0)
        for (int i = t; i < 128 * 17; i += 256) {
            int row = i / 17, dp = i - row * 17;
            int gp = lo + row;
            float2 v = make_float2(0.f, 0.f);
            if (gp < NPTS) v = *(const float2*)&msa[(size_t)gp * 34 + 2 * dp];
            ushort2 h; h.x = f2bf(v.x); h.y = f2bf(v.y);
            *(ushort2*)&lm[row * QS2 + 2 * dp] = h;
        }
        __syncthreads();
        // build B frags for this wave's point (row = w*32+mrow, both halves share)
        const unsigned short* mr = &lm[(w * 32 + mrow) * QS2];
        const int p = lo + w * 32 + mrow;
        float nrm = 0.f;
        ushort2 h33;
#pragma unroll
        for (int dp4 = 0; dp4 < 8; ++dp4) {    // shorts 0..31 via b64
            v4s h4 = *(const v4s*)(mr + 4 * dp4);
            nrm = fmaf(bf2fs(h4[0]), bf2fs(h4[0]), nrm);
            nrm = fmaf(bf2fs(h4[1]), bf2fs(h4[1]), nrm);
            nrm = fmaf(bf2fs(h4[2]), bf2fs(h4[2]), nrm);
            nrm = fmaf(bf2fs(h4[3]), bf2fs(h4[3]), nrm);
        }
        h33 = *(const ushort2*)(mr + 32);      // shorts 32,33
        nrm = fmaf(bf2f(h33.x), bf2f(h33.x), nrm);
        nrm = fmaf(bf2f(h33.y), bf2f(h33.y), nrm);
        if (p >= NPTS) nrm = 1e30f;            // invalid rows never pass
        v4s blo, bhi;
        blo = *(const v4s*)(mr + half * 8);
        bhi = *(const v4s*)(mr + half * 8 + 4);
        v8s B0 = __builtin_shufflevector(blo, bhi, 0, 1, 2, 3, 4, 5, 6, 7);
        blo = *(const v4s*)(mr + 16 + half * 8);
        bhi = *(const v4s*)(mr + 16 + half * 8 + 4);
        v8s B1 = __builtin_shufflevector(blo, bhi, 0, 1, 2, 3, 4, 5, 6, 7);
        v8s B2 = vz8;                          // k=32..39 (half0) / 40..47 (half1)
        if (half == 0) {
            B2[0] = (short)h33.x;              // m32
            B2[1] = (short)h33.y;              // m33
            B2[2] = (short)f2bf(nrm);          // k=34: pairs with q's -0.5
            B2[3] = (short)0x3F80;             // k=35: pairs with q's tau-term
        }
#pragma unroll
        for (int qt = 0; qt < 8; ++qt) {
            const unsigned short* qr = &lq[(qt * 32 + mrow) * QS2 + half * 8];
            v4s alo = *(const v4s*)(qr);
            v4s ahi = *(const v4s*)(qr + 4);
            v8s A0 = __builtin_shufflevector(alo, ahi, 0, 1, 2, 3, 4, 5, 6, 7);
            alo = *(const v4s*)(qr + 16);
            ahi = *(const v4s*)(qr + 16 + 4);
            v8s A1 = __builtin_shufflevector(alo, ahi, 0, 1, 2, 3, 4, 5, 6, 7);
            v4s a2 = *(const v4s*)(&lq[(qt * 32 + mrow) * QS2 + 32]);
            v8s A2 = (half == 0) ? __builtin_shufflevector(a2, vz4, 0, 1, 2, 3, 4, 5, 6, 7)
                                 : vz8;
            v16f acc;
#pragma unroll
            for (int i = 0; i < 16; ++i) acc[i] = 0.f;
            acc = __builtin_amdgcn_mfma_f32_32x32x16_bf16(A0, B0, acc, 0, 0, 0);
            acc = __builtin_amdgcn_mfma_f32_32x32x16_bf16(A1, B1, acc, 0, 0, 0);
            acc = __builtin_amdgcn_mfma_f32_32x32x16_bf16(A2, B2, acc, 0, 0, 0);
            unsigned hm = 0;
#pragma unroll
            for (int r = 0; r < 16; ++r) hm |= (acc[r] >= 0.f) ? (1u << r) : 0u;
            while (hm) {                       // ~1 hit per wave per chunk
                int r = __builtin_ctz(hm);
                hm &= hm - 1;
                int qq = qt * 32 + (r & 3) + 8 * (r >> 2) + 4 * half;
                int slot = atomicAdd(&lcount[qq], 1);
                if (slot < LCAP) {
                    lcand[qq * LCAP + slot] = p;
                } else {                       // rare overflow: direct to pair list
                    int dg = atomicAdd(cursor, 1);
                    if (dg < PCAP) pbuf[dg] = ((unsigned)qq << 19) | (unsigned)p;
                }
            }
        }
    }
    __syncthreads();
    // flush: prefix-scan lcount -> ONE cursor atomic -> compacted pair writes
    int n = lcount[t];
    if (n > LCAP) n = LCAP;
    lcount[t] = n;
    __syncthreads();
    for (int off = 1; off < 256; off <<= 1) {  // Hillis-Steele inclusive scan
        int v = (t >= off) ? lcount[t - off] : 0;
        __syncthreads();
        lcount[t] += v;
        __syncthreads();
    }
    int base_l = lcount[t] - n;
    if (t == 255) gbase = atomicAdd(cursor, lcount[255]);
    __syncthreads();
    for (int i = 0; i < n; ++i) {
        int dst = gbase + base_l + i;
        if (dst < PCAP) pbuf[dst] = ((unsigned)t << 19) | (unsigned)lcand[t * LCAP + i];
    }
}

// --- kernel 2: gather my pairs, exact fp32 rescore, top-10, softmax ---------
__global__ __launch_bounds__(256) void k_final(const float* __restrict__ obs,
                                               const float* __restrict__ act,
                                               const float* __restrict__ msa,
                                               const unsigned* __restrict__ pbuf,
                                               const int* __restrict__ cursor,
                                               const float* __restrict__ memQ,
                                               float* __restrict__ out) {
    __shared__ float ls[CAP];
    __shared__ int   li[CAP];
    __shared__ int   lcnt;
    __shared__ float rs[4];
    __shared__ int   ri[4];
    __shared__ float sel_s[TOPK];
    __shared__ int   sel_i[TOPK];
    const int b = blockIdx.x, t = threadIdx.x;
    const int lane = t & 63, wid = t >> 6;
    if (t == 0) lcnt = 0;
    __syncthreads();
    int npairs = *cursor;
    if (npairs > PCAP) npairs = PCAP;
    for (int j = t; j < npairs; j += 256) {     // coalesced scan of pair list
        unsigned pr = pbuf[j];
        if ((int)(pr >> 19) == b) {
            int s = atomicAdd(&lcnt, 1);
            if (s < CAP) li[s] = (int)(pr & 0x7FFFFu);
        }
    }
    __syncthreads();
    int cnt = lcnt;
    if (cnt > CAP) cnt = CAP;
    float q[34];
    load_q(obs, act, b, q);
    for (int j = t; j < cnt; j += 256) {        // exact fp32 re-scores
        const float* row = msa + (size_t)li[j] * 34;
        ls[j] = fmaf(-2.f, dot34(row, q), norm34(row));
    }
    __syncthreads();
    for (int k = 0; k < TOPK; ++k) {
        float bs = __builtin_inff();
        int   bi = 0x7fffffff;
        for (int j = t; j < cnt; j += 256) {
            float s = ls[j]; int i = li[j];
            if (s < bs || (s == bs && i < bi)) { bs = s; bi = i; }
        }
        for (int off = 32; off; off >>= 1) {
            float s2 = __shfl_down(bs, off);
            int   i2 = __shfl_down(bi, off);
            if (s2 < bs || (s2 == bs && i2 < bi)) { bs = s2; bi = i2; }
        }
        if (lane == 0) { rs[wid] = bs; ri[wid] = bi; }
        __syncthreads();
        if (t == 0) {
            float fs = rs[0]; int fi = ri[0];
#pragma unroll
            for (int ww = 1; ww < 4; ++ww) {
                if (rs[ww] < fs || (rs[ww] == fs && ri[ww] < fi)) { fs = rs[ww]; fi = ri[ww]; }
            }
            sel_s[k] = fs; sel_i[k] = fi;
        }
        __syncthreads();
        const int win = sel_i[k];
        for (int j = t; j < cnt; j += 256) {
            if (li[j] == win) ls[j] = __builtin_inff();
        }
        __syncthreads();
    }
    if (t == 0) {
        float m = sel_s[TOPK - 1];
        float wsum = 0.f, acc = 0.f;
#pragma unroll
        for (int k = 0; k < TOPK; ++k) {
            if (sel_i[k] == 0x7fffffff) continue;
            float w2 = expf(sel_s[k] - m);
            wsum += w2;
            acc = fmaf(w2, memQ[sel_i[k]], acc);
        }
        out[b] = acc / wsum;
    }
}

extern "C" void kernel_launch(void* const* d_in, const int* in_sizes, int n_in,
                              void* d_out, int out_size, void* d_ws, size_t ws_size,
                              hipStream_t stream) {
    const float* obs = (const float*)d_in[0];   // [256,32]
    const float* act = (const float*)d_in[1];   // [256,2]
    const float* msa = (const float*)d_in[2];   // [500000,34]
    const float* mq  = (const float*)d_in[3];   // [500000,1]
    float* out = (float*)d_out;                 // [256]

    char* ws = (char*)d_ws;
    unsigned short* qbf = (unsigned short*)ws;            // 18432 B
    int*      cursor = (int*)(ws + 18432);                // 4 B
    float*    minima = (float*)(ws + 32768);              // 1 MB (256 x 1024)
    unsigned* pbuf   = (unsigned*)(ws + 32768 + 1048576); // 2 MB
    // total ws use ~3.1 MB

    k_sample<<<SBLK, 256, 0, stream>>>(obs, act, msa, minima);
    k_tau   <<<NB, 64, 0, stream>>>(minima, obs, act, qbf, cursor);
    k_filter<<<FBLK, 256, 0, stream>>>(msa, qbf, cursor, pbuf);
    k_final <<<NB, 256, 0, stream>>>(obs, act, msa, pbuf, cursor, mq, out);
}

// Round 5
// 186.462 us; speedup vs baseline: 1.9564x; 1.9564x over previous
//
#include <hip/hip_runtime.h>
#include <math.h>

#define NPTS   500000
#define NB     256
#define TOPK   10
#define CAP    2048        // per-query candidate cap in k_final
#define SBLK   1024        // sample slices
#define SPER   16          // points per slice -> 16384-pt sample
#define MARGIN 2.0f        // bf16 worst-case score err ~0.5; 4x headroom
#define FBLK   768         // k_filter grid
#define NCHUNK 3907        // ceil(NPTS/128)
#define LCAP   8           // per-(block,query) local cap; overflow is SAFE now
#define QSR    40          // shorts per LDS row (80 B = 16-B aligned -> ds_read_b128)
#define PMAIN  393216      // main pair region (dwords)
#define OCAP   65536       // overflow pair region (dwords)

typedef short v4s  __attribute__((ext_vector_type(4)));
typedef short v8s  __attribute__((ext_vector_type(8)));
typedef float v16f __attribute__((ext_vector_type(16)));

__device__ __forceinline__ unsigned short f2bf(float f) {   // RNE
    unsigned u = __float_as_uint(f);
    unsigned r = u + 0x7FFFu + ((u >> 16) & 1u);
    return (unsigned short)(r >> 16);
}
__device__ __forceinline__ float bf2f(unsigned short h) {
    return __uint_as_float(((unsigned)h) << 16);
}
__device__ __forceinline__ float bf2fs(short h) {
    return __uint_as_float(((unsigned)(unsigned short)h) << 16);
}

// --- exact fp32 pieces: bitwise-identical order in k_sample and k_final -----
__device__ __forceinline__ float norm34(const float* __restrict__ r) {
    float a0 = 0.f, a1 = 0.f, a2 = 0.f, a3 = 0.f;
#pragma unroll
    for (int d = 0; d < 32; d += 4) {
        a0 = fmaf(r[d + 0], r[d + 0], a0);
        a1 = fmaf(r[d + 1], r[d + 1], a1);
        a2 = fmaf(r[d + 2], r[d + 2], a2);
        a3 = fmaf(r[d + 3], r[d + 3], a3);
    }
    a0 = fmaf(r[32], r[32], a0);
    a1 = fmaf(r[33], r[33], a1);
    return (a0 + a1) + (a2 + a3);
}
__device__ __forceinline__ float dot34(const float* __restrict__ r, const float* q) {
    float a0 = 0.f, a1 = 0.f, a2 = 0.f, a3 = 0.f;
#pragma unroll
    for (int d = 0; d < 32; d += 4) {
        a0 = fmaf(r[d + 0], q[d + 0], a0);
        a1 = fmaf(r[d + 1], q[d + 1], a1);
        a2 = fmaf(r[d + 2], q[d + 2], a2);
        a3 = fmaf(r[d + 3], q[d + 3], a3);
    }
    a0 = fmaf(r[32], q[32], a0);
    a1 = fmaf(r[33], q[33], a1);
    return (a0 + a1) + (a2 + a3);
}
// float4 LDS variant with IDENTICAL fma order -> bitwise-equal s
__device__ __forceinline__ float dot34_v4(const float4* __restrict__ r4, const float* q) {
    float a0 = 0.f, a1 = 0.f, a2 = 0.f, a3 = 0.f;
#pragma unroll
    for (int dp = 0; dp < 8; ++dp) {
        float4 v = r4[dp];
        a0 = fmaf(v.x, q[4 * dp + 0], a0);
        a1 = fmaf(v.y, q[4 * dp + 1], a1);
        a2 = fmaf(v.z, q[4 * dp + 2], a2);
        a3 = fmaf(v.w, q[4 * dp + 3], a3);
    }
    float2 t = *(const float2*)(r4 + 8);
    a0 = fmaf(t.x, q[32], a0);
    a1 = fmaf(t.y, q[33], a1);
    return (a0 + a1) + (a2 + a3);
}
__device__ __forceinline__ void load_q(const float* __restrict__ obs,
                                       const float* __restrict__ act, int b, float* q) {
#pragma unroll
    for (int d = 0; d < 32; ++d) q[d] = obs[b * 32 + d];
    q[32] = act[b * 2 + 0];
    q[33] = act[b * 2 + 1];
}

// --- kernel 0a: per-(query, 16-pt slice) min of s; minima transposed --------
__global__ __launch_bounds__(256, 4) void k_sample(const float* __restrict__ obs,
                                                   const float* __restrict__ act,
                                                   const float* __restrict__ msa,
                                                   float* __restrict__ minima) {
    __shared__ __align__(16) float sm[SPER * 36];
    __shared__ float smn[SPER];
    const int g = blockIdx.x, t = threadIdx.x;
    const int base = g * SPER;
    for (int i = t; i < SPER * 34; i += 256) {
        int row = i / 34, d = i - row * 34;
        sm[row * 36 + d] = msa[(size_t)base * 34 + i];
    }
    __syncthreads();
    if (t < SPER) smn[t] = norm34(&sm[t * 36]);
    __syncthreads();
    float q[34];
    load_q(obs, act, t, q);
    float best = __builtin_inff();
#pragma unroll
    for (int j = 0; j < SPER; ++j) {
        float s = fmaf(-2.f, dot34_v4((const float4*)&sm[j * 36], q), smn[j]);
        best = fminf(best, s);
    }
    minima[(size_t)t * SBLK + g] = best;          // transposed: k_tau coalesced
}

// --- kernel 0b: tau = 10th smallest of 1024 slice minima; q-hat; cursors=0 --
__global__ __launch_bounds__(64) void k_tau(const float* __restrict__ minima,
                                            const float* __restrict__ obs,
                                            const float* __restrict__ act,
                                            unsigned short* __restrict__ qbf,
                                            int* __restrict__ cursor) {
    const int b = blockIdx.x, lane = threadIdx.x;
    if (b == 0 && lane == 0) { cursor[0] = 0; cursor[1] = 0; }
    float v[16];
#pragma unroll
    for (int k = 0; k < 16; ++k) v[k] = minima[(size_t)b * SBLK + lane + 64 * k];
    float last = 0.f;
    for (int r = 0; r < TOPK; ++r) {
        float lm = v[0]; int la = 0;
#pragma unroll
        for (int k = 1; k < 16; ++k) { if (v[k] < lm) { lm = v[k]; la = k; } }
        float wm = lm;
        for (int off = 32; off; off >>= 1) wm = fminf(wm, __shfl_xor(wm, off));
        unsigned long long msk = __ballot(lm == wm);
        int first = (int)__builtin_ctzll(msk);
        if (lane == first) {
#pragma unroll
            for (int k = 0; k < 16; ++k) { if (k == la) v[k] = __builtin_inff(); }
        }
        last = wm;   // wave-uniform
    }
    // q-hat row (QSR shorts): [q(34), -0.5, (tau+MARGIN)/2, 0,0,0,0]
    float val = 0.f;
    if (lane < 32)       val = obs[b * 32 + lane];
    else if (lane < 34)  val = act[b * 2 + (lane - 32)];
    else if (lane == 34) val = -0.5f;
    else if (lane == 35) val = 0.5f * (last + MARGIN);
    if (lane < QSR) qbf[b * QSR + lane] = (lane < 36) ? f2bf(val) : (unsigned short)0;
}

// --- kernel 1: MFMA bf16 filter -> per-block query-sorted pair segments -----
// posq[g*256+q] = start_dword | (n<<20). Overflow -> safe side region.
__global__ __launch_bounds__(256, 4) void k_filter(const float* __restrict__ msa,
                                                   const unsigned short* __restrict__ qbf,
                                                   int* __restrict__ cursor,
                                                   unsigned* __restrict__ pbuf,
                                                   int* __restrict__ posq) {
    __shared__ __align__(16) unsigned short lq[NB * QSR];    // 20480 B
    __shared__ __align__(16) unsigned short lm[128 * QSR];   // 10240 B
    __shared__ int lcount[NB];                               // 1024 B
    __shared__ int lcand[NB * LCAP];                         // 8192 B
    __shared__ int gbase;
    const int g = blockIdx.x, t = threadIdx.x;
    lcount[t] = 0;
    // stage all 256 q-hat rows once (pre-converted bf16)
    const float4* qsrc = (const float4*)qbf;
    for (int i = t; i < NB * QSR / 8; i += 256)
        *(float4*)&lq[i * 8] = qsrc[i];
    const int w = t >> 6, lane = t & 63;
    const int mrow = lane & 31, half = lane >> 5;
    const v8s vz8 = (v8s)(short)0;
    for (int c = g; c < NCHUNK; c += FBLK) {
        const int lo = c * 128;
        __syncthreads();                       // lm reusable (covers lq/lcount on iter 0)
        for (int i = t; i < 128 * 17; i += 256) {
            int row = i / 17, dp = i - row * 17;
            int gp = lo + row;
            float2 v = make_float2(0.f, 0.f);
            if (gp < NPTS) v = *(const float2*)&msa[(size_t)gp * 34 + 2 * dp];
            ushort2 h; h.x = f2bf(v.x); h.y = f2bf(v.y);
            *(ushort2*)&lm[row * QSR + 2 * dp] = h;
        }
        __syncthreads();
        // B frags for this wave's point row (w*32+mrow)
        const unsigned short* mr = &lm[(w * 32 + mrow) * QSR];
        const int p = lo + w * 32 + mrow;
        float nrm = 0.f;
#pragma unroll
        for (int dp4 = 0; dp4 < 8; ++dp4) {
            v4s h4 = *(const v4s*)(mr + 4 * dp4);
            nrm = fmaf(bf2fs(h4[0]), bf2fs(h4[0]), nrm);
            nrm = fmaf(bf2fs(h4[1]), bf2fs(h4[1]), nrm);
            nrm = fmaf(bf2fs(h4[2]), bf2fs(h4[2]), nrm);
            nrm = fmaf(bf2fs(h4[3]), bf2fs(h4[3]), nrm);
        }
        ushort2 h33 = *(const ushort2*)(mr + 32);
        nrm = fmaf(bf2f(h33.x), bf2f(h33.x), nrm);
        nrm = fmaf(bf2f(h33.y), bf2f(h33.y), nrm);
        if (p >= NPTS) nrm = 1e30f;            // invalid rows never pass
        v8s B0 = *(const v8s*)(mr + half * 8);          // ds_read_b128
        v8s B1 = *(const v8s*)(mr + 16 + half * 8);
        v8s B2 = vz8;
        if (half == 0) {
            B2[0] = (short)h33.x;              // m32
            B2[1] = (short)h33.y;              // m33
            B2[2] = (short)f2bf(nrm);          // k=34: pairs with q's -0.5
            B2[3] = (short)0x3F80;             // k=35: pairs with q's tau-term
        }
#pragma unroll
        for (int qt = 0; qt < 8; ++qt) {
            const unsigned short* qr = &lq[(qt * 32 + mrow) * QSR];
            v8s A0 = *(const v8s*)(qr + half * 8);      // ds_read_b128
            v8s A1 = *(const v8s*)(qr + 16 + half * 8);
            v8s A2 = vz8;
            if (half == 0) A2 = *(const v8s*)(qr + 32); // shorts 32..39 (36..39 = 0)
            v16f acc;
#pragma unroll
            for (int i = 0; i < 16; ++i) acc[i] = 0.f;
            acc = __builtin_amdgcn_mfma_f32_32x32x16_bf16(A0, B0, acc, 0, 0, 0);
            acc = __builtin_amdgcn_mfma_f32_32x32x16_bf16(A1, B1, acc, 0, 0, 0);
            acc = __builtin_amdgcn_mfma_f32_32x32x16_bf16(A2, B2, acc, 0, 0, 0);
            unsigned hm = 0;
#pragma unroll
            for (int r = 0; r < 16; ++r) hm |= (acc[r] >= 0.f) ? (1u << r) : 0u;
            while (hm) {                       // ~1 hit per wave per chunk
                int r = __builtin_ctz(hm);
                hm &= hm - 1;
                int qq = qt * 32 + (r & 3) + 8 * (r >> 2) + 4 * half;
                int slot = atomicAdd(&lcount[qq], 1);
                if (slot < LCAP) {
                    lcand[qq * LCAP + slot] = p;
                } else {                       // SAFE overflow: side region
                    int dg = atomicAdd(cursor + 1, 1);
                    if (dg < OCAP) pbuf[PMAIN + dg] = ((unsigned)qq << 19) | (unsigned)p;
                }
            }
        }
    }
    __syncthreads();
    // flush: prefix-scan -> ONE cursor atomic -> compacted writes + pos table
    int n = lcount[t];
    if (n > LCAP) n = LCAP;
    lcount[t] = n;
    __syncthreads();
    for (int off = 1; off < 256; off <<= 1) {  // Hillis-Steele inclusive scan
        int v = (t >= off) ? lcount[t - off] : 0;
        __syncthreads();
        lcount[t] += v;
        __syncthreads();
    }
    int base_l = lcount[t] - n;
    if (t == 255) gbase = atomicAdd(cursor, lcount[255]);
    __syncthreads();
    int start = gbase + base_l;
    if (start + n > PMAIN) n = (start < PMAIN) ? (PMAIN - start) : 0;
    posq[g * NB + t] = start | (n << 20);      // coalesced, no atomic
    for (int i = 0; i < n; ++i)
        pbuf[start + i] = (unsigned)lcand[t * LCAP + i];
}

// --- kernel 2: gather my pair segments, exact fp32 rescore, top-10, softmax -
__global__ __launch_bounds__(256) void k_final(const float* __restrict__ obs,
                                               const float* __restrict__ act,
                                               const float* __restrict__ msa,
                                               const unsigned* __restrict__ pbuf,
                                               const int* __restrict__ posq,
                                               const int* __restrict__ cursor,
                                               const float* __restrict__ memQ,
                                               float* __restrict__ out) {
    __shared__ float ls[CAP];
    __shared__ int   li[CAP];
    __shared__ int   lcnt;
    __shared__ float rs[4];
    __shared__ int   ri[4];
    __shared__ float sel_s[TOPK];
    __shared__ int   sel_i[TOPK];
    const int b = blockIdx.x, t = threadIdx.x;
    const int lane = t & 63, wid = t >> 6;
    if (t == 0) lcnt = 0;
    __syncthreads();
    // gather exactly my segments (768 packed entries, 3 per thread)
    for (int g = t; g < FBLK; g += 256) {
        int packed = posq[g * NB + b];
        int n = (packed >> 20) & 0xF;
        int pos = packed & 0xFFFFF;
        if (n > 0) {
            int base = atomicAdd(&lcnt, n);
            for (int i = 0; i < n; ++i) {
                int dst = base + i;
                if (dst < CAP) li[dst] = (int)pbuf[pos + i];
            }
        }
    }
    // overflow region (normally empty)
    int novf = cursor[1];
    if (novf > OCAP) novf = OCAP;
    for (int j = t; j < novf; j += 256) {
        unsigned pr = pbuf[PMAIN + j];
        if ((int)(pr >> 19) == b) {
            int s = atomicAdd(&lcnt, 1);
            if (s < CAP) li[s] = (int)(pr & 0x7FFFFu);
        }
    }
    __syncthreads();
    int cnt = lcnt;
    if (cnt > CAP) cnt = CAP;
    float q[34];
    load_q(obs, act, b, q);
    for (int j = t; j < cnt; j += 256) {        // exact fp32 re-scores
        const float* row = msa + (size_t)li[j] * 34;
        ls[j] = fmaf(-2.f, dot34(row, q), norm34(row));
    }
    __syncthreads();
    for (int k = 0; k < TOPK; ++k) {
        float bs = __builtin_inff();
        int   bi = 0x7fffffff;
        for (int j = t; j < cnt; j += 256) {
            float s = ls[j]; int i = li[j];
            if (s < bs || (s == bs && i < bi)) { bs = s; bi = i; }
        }
        for (int off = 32; off; off >>= 1) {
            float s2 = __shfl_down(bs, off);
            int   i2 = __shfl_down(bi, off);
            if (s2 < bs || (s2 == bs && i2 < bi)) { bs = s2; bi = i2; }
        }
        if (lane == 0) { rs[wid] = bs; ri[wid] = bi; }
        __syncthreads();
        if (t == 0) {
            float fs = rs[0]; int fi = ri[0];
#pragma unroll
            for (int ww = 1; ww < 4; ++ww) {
                if (rs[ww] < fs || (rs[ww] == fs && ri[ww] < fi)) { fs = rs[ww]; fi = ri[ww]; }
            }
            sel_s[k] = fs; sel_i[k] = fi;
        }
        __syncthreads();
        const int win = sel_i[k];
        for (int j = t; j < cnt; j += 256) {
            if (li[j] == win) ls[j] = __builtin_inff();
        }
        __syncthreads();
    }
    if (t == 0) {
        float m = sel_s[TOPK - 1];
        float wsum = 0.f, acc = 0.f;
#pragma unroll
        for (int k = 0; k < TOPK; ++k) {
            if (sel_i[k] == 0x7fffffff) continue;
            float w2 = expf(sel_s[k] - m);
            wsum += w2;
            acc = fmaf(w2, memQ[sel_i[k]], acc);
        }
        out[b] = acc / wsum;
    }
}

extern "C" void kernel_launch(void* const* d_in, const int* in_sizes, int n_in,
                              void* d_out, int out_size, void* d_ws, size_t ws_size,
                              hipStream_t stream) {
    const float* obs = (const float*)d_in[0];   // [256,32]
    const float* act = (const float*)d_in[1];   // [256,2]
    const float* msa = (const float*)d_in[2];   // [500000,34]
    const float* mq  = (const float*)d_in[3];   // [500000,1]
    float* out = (float*)d_out;                 // [256]

    char* ws = (char*)d_ws;
    unsigned short* qbf = (unsigned short*)ws;                  // 20480 B
    int*      cursor = (int*)(ws + 20480);                      // 8 B
    float*    minima = (float*)(ws + 32768);                    // 1 MB
    int*      posq   = (int*)(ws + 32768 + 1048576);            // 786432 B
    unsigned* pbuf   = (unsigned*)(ws + 32768 + 1048576 + 786432); // 1835008 B
    // total ws use ~3.7 MB

    k_sample<<<SBLK, 256, 0, stream>>>(obs, act, msa, minima);
    k_tau   <<<NB, 64, 0, stream>>>(minima, obs, act, qbf, cursor);
    k_filter<<<FBLK, 256, 0, stream>>>(msa, qbf, cursor, pbuf, posq);
    k_final <<<NB, 256, 0, stream>>>(obs, act, msa, pbuf, posq, cursor, mq, out);
}